// Round 7
// baseline (353.329 us; speedup 1.0000x reference)
//
#include <hip/hip_runtime.h>

// ---------------------------------------------------------------------------
// HeteroGNN fused pipeline for MI355X (gfx950).
//   loc_h = relu(loc_x @ W_loc + b_loc)          [100000, 64]
//   evt_h = relu(evt_x @ W_evt + b_evt)          [200000, 64]
//   agg   = segment_mean(evt_h[src] -> dst)      (bucketed CSR gather)
//   h2    = relu(agg @ W_l + b_l + loc_h @ W_r)  (MFMA)
//   h1    = relu(h2 @ W_h1 + b_h1)               (MFMA)
//   out   = h1 @ W_h2 + b_h2                     [100000]
// R7: proj_both restructured as persistent-strip kernel: B-frags + bias
// loaded once per wave, grid-stride over ~4 strips/wave with manual A
// prefetch. (R6 version re-loaded the full 16KB weight per 16-row strip ->
// latency-bound at 2.4% MfmaUtil, 70us for 18us of HBM traffic.)
// ---------------------------------------------------------------------------

#define N_LOC 100000
#define N_EVT 200000
#define E_CNT 1000000
#define NTILES 6250   // N_LOC / 16
#define NBKT   256
#define BKT_L  391    // locations per bucket (255*391=99705 <= 99999)
#define CAPG   6000   // per-bucket capacity (avg 3906, sigma 62)
#define QCAP   32     // passA LDS queue depth per bucket
#define PERB   7813   // edges per passA block (128 blocks)

// proj grid: evt strips 12500 (blocks 0..767), loc strips 6250 (768..1151)
#define PROJ_EVT_BLK 768
#define PROJ_LOC_BLK 384

typedef __attribute__((ext_vector_type(8))) short short8;   // 8 x bf16
typedef __attribute__((ext_vector_type(4))) float floatx4;  // MFMA C/D frag

__device__ __forceinline__ float b2f(unsigned short u) {
    unsigned int x = ((unsigned int)u) << 16;
    return __builtin_bit_cast(float, x);
}
__device__ __forceinline__ unsigned short f2b(float f) {
    unsigned int x = __builtin_bit_cast(unsigned int, f);
    unsigned int r = (x + 0x7fffu + ((x >> 16) & 1u)) >> 16;  // RNE
    return (unsigned short)r;
}
__device__ __forceinline__ float loadf(const void* p, int f32, size_t i) {
    return f32 ? ((const float*)p)[i] : b2f(((const unsigned short*)p)[i]);
}

// ---------------------------------------------------------------------------
// KA: detect + zero + permute, one launch, 28 blocks.
// ---------------------------------------------------------------------------
__global__ __launch_bounds__(256) void prep_kernel(
    const void* t0, const void* t1, const int* eidx,
    const void* t3, const void* t4, const void* t5, const void* t6,
    const void* t7, const void* t8, const void* t9, const void* t10,
    const void* t11, const void* t12, const void* t13,
    int* flags, int* gbc, unsigned short* __restrict__ wp_all) {
    int b = blockIdx.x, tid = threadIdx.x;
    __shared__ int s0, s1;

    if (b == 14) { gbc[tid] = 0; return; }

    if (b >= 15) {                           // permute, self-detecting
        int pb = b - 15;
        const void* W; int K, N, bstart, off;
        if (pb < 4)       { W = t5;  K = 128; N = 64; bstart = 0;  off = 0; }
        else if (pb < 8)  { W = t3;  K = 128; N = 64; bstart = 4;  off = 8192; }
        else if (pb < 10) { W = t7;  K = 64;  N = 64; bstart = 8;  off = 16384; }
        else if (pb < 12) { W = t9;  K = 64;  N = 64; bstart = 10; off = 20480; }
        else              { W = t10; K = 64;  N = 32; bstart = 12; off = 24576; }
        if (tid == 0) s0 = 0;
        __syncthreads();
        int nsamp = 2 * K * N; if (nsamp > 1024) nsamp = 1024;
        const unsigned short* h = (const unsigned short*)W;
        int susp = 0;
        for (int i = tid; i < nsamp; i += 256)
            if (((h[i] >> 7) & 0xFF) >= 0x90) susp++;
        if (susp) atomicAdd(&s0, susp);
        __syncthreads();
        int f32 = (s0 * 16 >= nsamp) ? 1 : 0;

        int idx  = (pb - bstart) * 256 + tid;
        int nk   = K >> 5;
        int f    = idx >> 6;
        int lane = idx & 63;
        int t  = f / nk;
        int kk = f - t * nk;
        int n  = t * 16 + (lane & 15);
        int k0 = kk * 32 + (lane >> 4) * 8;
        unsigned short tmp[8];
#pragma unroll
        for (int j = 0; j < 8; ++j) {
            size_t src = (size_t)(k0 + j) * N + n;
            tmp[j] = f32 ? f2b(((const float*)W)[src])
                         : ((const unsigned short*)W)[src];
        }
#pragma unroll
        for (int j = 0; j < 8; ++j) wp_all[(size_t)off + (size_t)idx * 8 + j] = tmp[j];
        return;
    }

    if (tid == 0) { s0 = 0; s1 = 0; }
    __syncthreads();
    if (b == 13) {   // edge_index: int64 => all odd 32-bit words zero
        if (tid < 128) {
            if (eidx[2 * tid] != 0) atomicAdd(&s0, 1);
            if (eidx[2 * tid + 1] != 0) atomicAdd(&s1, 1);
        }
        __syncthreads();
        if (tid == 0) flags[2] = (s1 == 0 && s0 > 32) ? 1 : 0;
        return;
    }
    const void* ptrs[13] = {t0, t1, t3, t4, t5, t6, t7, t8, t9, t10, t11, t12, t13};
    const int   cnts[13] = {12800000, 25600000, 8192, 64, 8192, 64,
                            4096, 64, 4096, 2048, 32, 32, 1};
    const int   slot[13] = {0, 1, 3, 4, 5, 6, 7, 8, 9, 10, 11, 12, 13};
    int nsamp = 2 * cnts[b];
    if (nsamp > 1024) nsamp = 1024;
    const unsigned short* h = (const unsigned short*)ptrs[b];
    int susp = 0;
    for (int i = tid; i < nsamp; i += 256)
        if (((h[i] >> 7) & 0xFF) >= 0x90) susp++;
    if (susp) atomicAdd(&s0, susp);
    __syncthreads();
    if (tid == 0) flags[slot[b]] = (s0 * 16 >= nsamp) ? 1 : 0;
}

// ---------------------------------------------------------------------------
// helper: load one 16-row A strip (row m, quad-chunked) as 4 bf16x8 frags
// ---------------------------------------------------------------------------
__device__ __forceinline__ void load_a_frags(
    const void* __restrict__ X, int fx, int m, int quad, short8* a) {
    if (fx) {
        const float* xr = (const float*)X + (size_t)m * 128 + quad * 8;
#pragma unroll
        for (int kk = 0; kk < 4; ++kk) {
            float4 p0 = *reinterpret_cast<const float4*>(xr + kk * 32);
            float4 p1 = *reinterpret_cast<const float4*>(xr + kk * 32 + 4);
            short8 v;
            v[0] = (short)f2b(p0.x); v[1] = (short)f2b(p0.y);
            v[2] = (short)f2b(p0.z); v[3] = (short)f2b(p0.w);
            v[4] = (short)f2b(p1.x); v[5] = (short)f2b(p1.y);
            v[6] = (short)f2b(p1.z); v[7] = (short)f2b(p1.w);
            a[kk] = v;
        }
    } else {
        const unsigned short* xr = (const unsigned short*)X + (size_t)m * 128 + quad * 8;
#pragma unroll
        for (int kk = 0; kk < 4; ++kk)
            a[kk] = *reinterpret_cast<const short8*>(xr + kk * 32);
    }
}

// ---------------------------------------------------------------------------
// K1: persistent-strip projections. Blocks [0,768): evt, [768,1152): loc.
// Wave loads B-frags + bias ONCE, then grid-strides over 16-row strips with
// manual A prefetch. N_EVT, N_LOC both divisible by 16 -> no bound checks.
// ---------------------------------------------------------------------------
__global__ __launch_bounds__(256) void proj_both_kernel(
    const void* __restrict__ evt_x, const void* __restrict__ loc_x,
    const unsigned short* __restrict__ wp_all,
    const void* __restrict__ b_evt, const void* __restrict__ b_loc,
    unsigned short* __restrict__ evt_h, unsigned short* __restrict__ loc_h,
    const int* __restrict__ flags) {
    int blk = blockIdx.x;
    int tid  = threadIdx.x;
    int lane = tid & 63;
    int wv   = tid >> 6;
    int l15  = lane & 15;
    int quad = lane >> 4;

    const void* X; const unsigned short* Wp; const void* bias;
    unsigned short* Y; int fx, fb, wid, nwaves, nstrips;
    if (blk < PROJ_EVT_BLK) {
        X = evt_x; Wp = wp_all;        bias = b_evt; Y = evt_h;
        fx = flags[1]; fb = flags[6];
        wid = blk * 4 + wv; nwaves = PROJ_EVT_BLK * 4; nstrips = N_EVT / 16;
    } else {
        X = loc_x; Wp = wp_all + 8192; bias = b_loc; Y = loc_h;
        fx = flags[0]; fb = flags[4];
        wid = (blk - PROJ_EVT_BLK) * 4 + wv; nwaves = PROJ_LOC_BLK * 4;
        nstrips = N_LOC / 16;
    }

    short8 b[16];
#pragma unroll
    for (int f = 0; f < 16; ++f)
        b[f] = *reinterpret_cast<const short8*>(Wp + ((size_t)(f * 64 + lane)) * 8);
    float bv[4];
#pragma unroll
    for (int t = 0; t < 4; ++t) bv[t] = loadf(bias, fb, t * 16 + l15);

    int s = wid;
    if (s >= nstrips) return;
    short8 a[4], a2[4];
    load_a_frags(X, fx, s * 16 + l15, quad, a);

    for (; s < nstrips; s += nwaves) {
        int sn = s + nwaves;
        if (sn < nstrips) load_a_frags(X, fx, sn * 16 + l15, quad, a2);

        floatx4 acc[4];
#pragma unroll
        for (int t = 0; t < 4; ++t) acc[t] = (floatx4)0.0f;
#pragma unroll
        for (int kk = 0; kk < 4; ++kk) {
#pragma unroll
            for (int t = 0; t < 4; ++t)
                acc[t] = __builtin_amdgcn_mfma_f32_16x16x32_bf16(
                    a[kk], b[t * 4 + kk], acc[t], 0, 0, 0);
        }

        int row_base = s * 16;
#pragma unroll
        for (int t = 0; t < 4; ++t) {
#pragma unroll
            for (int r = 0; r < 4; ++r) {
                float v = acc[t][r] + bv[t];
                v = v > 0.0f ? v : 0.0f;
                Y[(size_t)(row_base + quad * 4 + r) * 64 + t * 16 + l15] = f2b(v);
            }
        }
#pragma unroll
        for (int kk = 0; kk < 4; ++kk) a[kk] = a2[kk];
    }
}

// ---------------------------------------------------------------------------
// K2a (passA): bucket edges by dst/391 via LDS queues; flush 128B bursts.
// ---------------------------------------------------------------------------
__global__ __launch_bounds__(256) void bucket_kernel(
    const int* __restrict__ eidx, uint2* __restrict__ bkt,
    int* __restrict__ gbc, const int* __restrict__ flags) {
    __shared__ uint2 queue[NBKT][QCAP];   // 64 KB
    __shared__ int qcnt[NBKT];
    int tid = threadIdx.x, blk = blockIdx.x;
    qcnt[tid] = 0;
    __syncthreads();
    int f64 = flags[2];
    const long long* e64 = (const long long*)eidx;
    int e0 = blk * PERB;
    int e1 = e0 + PERB; if (e1 > E_CNT) e1 = E_CNT;
    const int rounds = (PERB + 255) / 256;

    for (int r = 0; r < rounds; ++r) {
        int e = e0 + r * 256 + tid;
        if (e < e1) {
            int src, dst;
            if (f64) { src = (int)e64[e]; dst = (int)e64[E_CNT + e]; }
            else     { src = eidx[e];     dst = eidx[E_CNT + e]; }
            if ((unsigned)dst < (unsigned)N_LOC && (unsigned)src < (unsigned)N_EVT) {
                int bk = dst / BKT_L;
                int pos = atomicAdd(&qcnt[bk], 1);
                if (pos < QCAP) {
                    queue[bk][pos] = make_uint2((unsigned)src, (unsigned)dst);
                } else {   // overflow (rare): direct store
                    int p = atomicAdd(&gbc[bk], 1);
                    if (p < CAPG) bkt[(size_t)bk * CAPG + p] = make_uint2(src, dst);
                }
            }
        }
        __syncthreads();
        // flush phase: thread t owns bucket t
        int n = qcnt[tid]; if (n > QCAP) n = QCAP;
        while (n >= 16) {
            int gp = atomicAdd(&gbc[tid], 16);
            if (gp + 16 <= CAPG) {
                uint2* d = bkt + (size_t)tid * CAPG + gp;
#pragma unroll
                for (int j = 0; j < 16; ++j) d[j] = queue[tid][j];
            }
#pragma unroll
            for (int j = 16; j < QCAP; ++j) queue[tid][j - 16] = queue[tid][j];
            n -= 16;
        }
        qcnt[tid] = n;
        __syncthreads();
    }
    // tail flush
    int n = qcnt[tid]; if (n > QCAP) n = QCAP;
    if (n > 0) {
        int gp = atomicAdd(&gbc[tid], n);
        for (int j = 0; j < n; ++j)
            if (gp + j < CAPG) bkt[(size_t)tid * CAPG + gp + j] = queue[tid][j];
    }
}

// ---------------------------------------------------------------------------
// K2b: exclusive scan of 256 bucket counts.
// ---------------------------------------------------------------------------
__global__ void scan_gbc_kernel(const int* __restrict__ gbc,
                                int* __restrict__ bbase) {
    __shared__ int sh[256];
    int t = threadIdx.x;
    int v = gbc[t]; if (v > CAPG) v = CAPG;
    sh[t] = v;
    __syncthreads();
    for (int d = 1; d < 256; d <<= 1) {
        int x = (t >= d) ? sh[t - d] : 0;
        __syncthreads();
        sh[t] += x;
        __syncthreads();
    }
    bbase[t] = sh[t] - v;
}

// ---------------------------------------------------------------------------
// K2c (passB): per-bucket local CSR build in LDS; all global writes coalesced.
// ---------------------------------------------------------------------------
__global__ __launch_bounds__(256) void csr_build_kernel(
    const uint2* __restrict__ bkt, const int* __restrict__ gbc,
    const int* __restrict__ bbase,
    int* __restrict__ rowptr, int* __restrict__ csr) {
    __shared__ int lcnt[512];
    __shared__ int lscan[512];
    __shared__ int lcsr[CAPG];
    int b = blockIdx.x, tid = threadIdx.x;
    int loc0 = b * BKT_L;
    int nloc = N_LOC - loc0; if (nloc > BKT_L) nloc = BKT_L;
    int cntE = gbc[b]; if (cntE > CAPG) cntE = CAPG;
    int base = bbase[b];
    const uint2* bp = bkt + (size_t)b * CAPG;

    int i0 = tid, i1 = tid + 256;
    lcnt[i0] = 0; lcnt[i1] = 0;
    __syncthreads();
    for (int i = tid; i < cntE; i += 256) {
        int d = (int)bp[i].y - loc0;
        atomicAdd(&lcnt[d], 1);
    }
    __syncthreads();
    lscan[i0] = lcnt[i0]; lscan[i1] = lcnt[i1];
    __syncthreads();
    for (int d = 1; d < 512; d <<= 1) {
        int v0 = (i0 >= d) ? lscan[i0 - d] : 0;
        int v1 = (i1 >= d) ? lscan[i1 - d] : 0;
        __syncthreads();
        lscan[i0] += v0; lscan[i1] += v1;
        __syncthreads();
    }
    for (int i = tid; i < nloc; i += 256) {
        int excl = lscan[i] - lcnt[i];
        rowptr[loc0 + i] = base + excl;
        lcnt[i] = excl;
    }
    if (b == NBKT - 1 && tid == 0) rowptr[N_LOC] = base + cntE;
    __syncthreads();
    for (int i = tid; i < cntE; i += 256) {
        uint2 pr = bp[i];
        int d = (int)pr.y - loc0;
        int p = atomicAdd(&lcnt[d], 1);
        if (p < CAPG) lcsr[p] = (int)pr.x;
    }
    __syncthreads();
    for (int i = tid; i < cntE; i += 256) csr[base + i] = lcsr[i];
}

// ---------------------------------------------------------------------------
// K3: gather-mean, 1 wave per row, lane = column. Predicated 4-wide groups.
// ---------------------------------------------------------------------------
__global__ __launch_bounds__(256) void aggregate_kernel(
    const unsigned short* __restrict__ evt_h,
    const int* __restrict__ rowptr, const int* __restrict__ csr,
    unsigned short* __restrict__ agg, int N) {
    int wid  = (blockIdx.x * 256 + threadIdx.x) >> 6;
    int lane = threadIdx.x & 63;
    if (wid >= N) return;
    int e0 = rowptr[wid], e1 = rowptr[wid + 1];
    float acc = 0.0f;
    for (int j = e0; j < e1; j += 4) {
        int c1 = j + 1 < e1, c2 = j + 2 < e1, c3 = j + 3 < e1;
        int s0 = csr[j];
        int s1 = csr[c1 ? j + 1 : j];
        int s2 = csr[c2 ? j + 2 : j];
        int s3 = csr[c3 ? j + 3 : j];
        float v0 = b2f(evt_h[(size_t)s0 * 64 + lane]);
        float v1 = b2f(evt_h[(size_t)s1 * 64 + lane]);
        float v2 = b2f(evt_h[(size_t)s2 * 64 + lane]);
        float v3 = b2f(evt_h[(size_t)s3 * 64 + lane]);
        acc += v0;
        if (c1) acc += v1;
        if (c2) acc += v2;
        if (c3) acc += v3;
    }
    float inv = (e1 > e0) ? 1.0f / (float)(e1 - e0) : 0.0f;
    agg[(size_t)wid * 64 + lane] = f2b(acc * inv);
}

// ---------------------------------------------------------------------------
// K4: SAGE + head via MFMA. One wave = 16-row tile; wave-private LDS.
// ---------------------------------------------------------------------------
__global__ __launch_bounds__(256) void head_kernel(
    const unsigned short* __restrict__ agg,
    const unsigned short* __restrict__ loc_h,
    const unsigned short* __restrict__ wp_all,
    const void* __restrict__ bl, const void* __restrict__ bh1,
    const void* __restrict__ wh2, const void* __restrict__ bh2,
    void* __restrict__ out, const int* __restrict__ flags) {
    __shared__ unsigned short h2s[4][16 * 64];
    int tid = threadIdx.x, lane = tid & 63, wv = tid >> 6;
    int tile = blockIdx.x * 4 + wv;
    if (tile >= NTILES) return;
    int l15 = lane & 15, quad = lane >> 4;
    int fbl = flags[8], fbh1 = flags[11], fwh2 = flags[12], fbh2 = flags[13];
    int fout = flags[0];
    int base = tile * 16;
    const unsigned short* wp_l  = wp_all + 16384;
    const unsigned short* wp_r  = wp_all + 20480;
    const unsigned short* wp_h1 = wp_all + 24576;

    short8 bwl[8], bwr[8], bw1[4];
#pragma unroll
    for (int f = 0; f < 8; ++f) {
        bwl[f] = *reinterpret_cast<const short8*>(wp_l + ((size_t)(f * 64 + lane)) * 8);
        bwr[f] = *reinterpret_cast<const short8*>(wp_r + ((size_t)(f * 64 + lane)) * 8);
    }
#pragma unroll
    for (int f = 0; f < 4; ++f)
        bw1[f] = *reinterpret_cast<const short8*>(wp_h1 + ((size_t)(f * 64 + lane)) * 8);

    short8 aA[2], aL[2];
#pragma unroll
    for (int kk = 0; kk < 2; ++kk) {
        aA[kk] = *reinterpret_cast<const short8*>(
            agg + (size_t)(base + l15) * 64 + kk * 32 + quad * 8);
        aL[kk] = *reinterpret_cast<const short8*>(
            loc_h + (size_t)(base + l15) * 64 + kk * 32 + quad * 8);
    }

    floatx4 acc[4];
#pragma unroll
    for (int t = 0; t < 4; ++t) acc[t] = (floatx4)0.0f;
#pragma unroll
    for (int kk = 0; kk < 2; ++kk) {
#pragma unroll
        for (int t = 0; t < 4; ++t) {
            acc[t] = __builtin_amdgcn_mfma_f32_16x16x32_bf16(
                aA[kk], bwl[t * 2 + kk], acc[t], 0, 0, 0);
            acc[t] = __builtin_amdgcn_mfma_f32_16x16x32_bf16(
                aL[kk], bwr[t * 2 + kk], acc[t], 0, 0, 0);
        }
    }

#pragma unroll
    for (int t = 0; t < 4; ++t) {
        float bb = loadf(bl, fbl, t * 16 + l15);
#pragma unroll
        for (int r = 0; r < 4; ++r) {
            float v = acc[t][r] + bb;
            v = v > 0.0f ? v : 0.0f;
            h2s[wv][(quad * 4 + r) * 64 + t * 16 + l15] = f2b(v);
        }
    }
    short8 aH[2];
#pragma unroll
    for (int kk = 0; kk < 2; ++kk)
        aH[kk] = *reinterpret_cast<const short8*>(
            &h2s[wv][l15 * 64 + kk * 32 + quad * 8]);

    floatx4 a1[2];
#pragma unroll
    for (int t = 0; t < 2; ++t) a1[t] = (floatx4)0.0f;
#pragma unroll
    for (int kk = 0; kk < 2; ++kk)
#pragma unroll
        for (int t = 0; t < 2; ++t)
            a1[t] = __builtin_amdgcn_mfma_f32_16x16x32_bf16(
                aH[kk], bw1[t * 2 + kk], a1[t], 0, 0, 0);

    float s[4] = {0.f, 0.f, 0.f, 0.f};
#pragma unroll
    for (int t = 0; t < 2; ++t) {
        float bb = loadf(bh1, fbh1, t * 16 + l15);
        float w2 = loadf(wh2, fwh2, t * 16 + l15);
#pragma unroll
        for (int r = 0; r < 4; ++r) {
            float v = a1[t][r] + bb;
            v = v > 0.0f ? v : 0.0f;
            s[r] += v * w2;
        }
    }
#pragma unroll
    for (int r = 0; r < 4; ++r) {
        s[r] += __shfl_xor(s[r], 1);
        s[r] += __shfl_xor(s[r], 2);
        s[r] += __shfl_xor(s[r], 4);
        s[r] += __shfl_xor(s[r], 8);
    }
    float bb2 = loadf(bh2, fbh2, 0);
#pragma unroll
    for (int r = 0; r < 4; ++r) {
        if (l15 == r) {
            int row = base + quad * 4 + r;
            float v = s[r] + bb2;
            if (fout) ((float*)out)[row] = v;
            else      ((unsigned short*)out)[row] = f2b(v);
        }
    }
}

// ---------------------------------------------------------------------------
// Workspace layout (bytes):
//   0:          evt_h    bf16 [200000,64] (25,600,000)
//   25600000:   loc_h    bf16 [100000,64] (12,800,000)
//   38400000:   csr      int [1M]         (4,000,000)
//   42400000:   rowptr   int [100001]     (400,016)
//   42800016:   gbc      int [256]        (1,024)
//   42801040:   bbase    int [256]        (1,024)
//   42802064:   wp_all   bf16 [26624]     (53,248)
//   42855312:   flags    int[16]          (64)
//   42855376:   bkt uint2[256][6000] (12,288,000) / agg bf16 (12,800,000)
//               (temporally disjoint union; ends 55,655,376)
// ---------------------------------------------------------------------------
extern "C" void kernel_launch(void* const* d_in, const int* in_sizes, int n_in,
                              void* d_out, int out_size, void* d_ws, size_t ws_size,
                              hipStream_t stream) {
    (void)in_sizes; (void)n_in; (void)out_size; (void)ws_size;
    const void* loc_x = d_in[0];
    const void* evt_x = d_in[1];
    const int*  eidx  = (const int*)d_in[2];
    const void* W_loc = d_in[3];
    const void* b_loc = d_in[4];
    const void* W_evt = d_in[5];
    const void* b_evt = d_in[6];
    const void* W_l   = d_in[7];
    const void* b_l   = d_in[8];
    const void* W_r   = d_in[9];
    const void* W_h1  = d_in[10];
    const void* b_h1  = d_in[11];
    const void* W_h2  = d_in[12];
    const void* b_h2  = d_in[13];

    char* ws = (char*)d_ws;
    unsigned short* evt_h  = (unsigned short*)(ws);
    unsigned short* loc_h  = (unsigned short*)(ws + 25600000);
    int*            csr    = (int*)(ws + 38400000);
    int*            rowptr = (int*)(ws + 42400000);
    int*            gbc    = (int*)(ws + 42800016);
    int*            bbase  = (int*)(ws + 42801040);
    unsigned short* wp_all = (unsigned short*)(ws + 42802064);
    int*            flags  = (int*)(ws + 42855312);
    uint2*          bkt    = (uint2*)(ws + 42855376);
    unsigned short* agg    = (unsigned short*)(ws + 42855376);

    prep_kernel<<<28, 256, 0, stream>>>(
        loc_x, evt_x, eidx, W_loc, b_loc, W_evt, b_evt,
        W_l, b_l, W_r, W_h1, b_h1, W_h2, b_h2,
        flags, gbc, wp_all);

    proj_both_kernel<<<PROJ_EVT_BLK + PROJ_LOC_BLK, 256, 0, stream>>>(
        evt_x, loc_x, wp_all, b_evt, b_loc, evt_h, loc_h, flags);

    bucket_kernel<<<128, 256, 0, stream>>>(eidx, bkt, gbc, flags);
    scan_gbc_kernel<<<1, 256, 0, stream>>>(gbc, bbase);
    csr_build_kernel<<<NBKT, 256, 0, stream>>>(bkt, gbc, bbase, rowptr, csr);

    aggregate_kernel<<<(N_LOC + 3) / 4, 256, 0, stream>>>(evt_h, rowptr, csr,
                                                          agg, N_LOC);

    head_kernel<<<(NTILES + 3) / 4, 256, 0, stream>>>(
        agg, loc_h, wp_all, b_l, b_h1, W_h2, b_h2, d_out, flags);
}